// Round 5
// baseline (253.931 us; speedup 1.0000x reference)
//
#include <hip/hip_runtime.h>

// GlobalChannelAttention: B=16, C=256, H*W=4096
//
// Pipeline (TN-form GEMMs: C[M,N] = sum_k A[m][k]*B[n][k], K contiguous):
//   1. prep_w: w1 -> W1Th (bf16 transposed), w2/w3 -> hi/lo bf16
//   2. gram: G[b] = X X^T read DIRECTLY from x f32 (hi/lo split in staging),
//      one 512-thr block per (batch, n-split/16) computes full 256x256;
//      A-fragments hoisted (24 ds_read_b128/wave/iter, not 72);
//      xsum folded into staging. f32 partials -> reduce to G hi/lo.
//   3. T3 = W3*G (G symmetric), Lt = T3*W2^T == logits TRANSPOSED (Lt[d][a])
//   4. global softmax (pass1 + fused combine/write pass3, coalesced) -> WT bf16
//   5. out = (WT*W1)*X + WT*b1:  Mh = WT*W1T (bf16), bb = WT·b1,
//      out = Mh*X^T + bb -- B operand read straight from x f32 with in-LDS
//      transpose (pair-packed b32 writes, XOR-swizzled e-blocks).
//
// Precision: logit chain bf16 hi/lo x3 (err ~2^-17 rel); out chain plain bf16.

typedef unsigned short u16;
typedef __attribute__((ext_vector_type(8))) short short8;
typedef __attribute__((ext_vector_type(4))) float floatx4;

__device__ __forceinline__ u16 f2b(float f) {
  union { float f; unsigned int u; } v; v.f = f;
  unsigned int u = v.u;
  return (u16)((u + 0x7fffu + ((u >> 16) & 1u)) >> 16);  // RNE
}
__device__ __forceinline__ float b2f(u16 h) {
  union { unsigned int u; float f; } v; v.u = ((unsigned int)h) << 16;
  return v.f;
}

// ---------------- merged W prep: transpose w1 + split w2/w3 ----------------
__global__ __launch_bounds__(256) void prep_w_kernel(
    const float* __restrict__ w1, const float* __restrict__ w2, const float* __restrict__ w3,
    u16* __restrict__ W1Th, u16* __restrict__ W2h, u16* __restrict__ W2l,
    u16* __restrict__ W3h, u16* __restrict__ W3l) {
  const int blk = blockIdx.x, t = threadIdx.x;
  if (blk < 64) {  // W1Th[e][c] = w1[c][e]
    __shared__ float tile[32][33];
    const int e0 = (blk & 7) * 32, c0 = (blk >> 3) * 32;
    const int tx = t & 31, ty = t >> 5;
#pragma unroll
    for (int i = 0; i < 4; ++i)
      tile[ty + i * 8][tx] = w1[(c0 + ty + i * 8) * 256 + e0 + tx];
    __syncthreads();
#pragma unroll
    for (int i = 0; i < 4; ++i)
      W1Th[(e0 + ty + i * 8) * 256 + c0 + tx] = f2b(tile[tx][ty + i * 8]);
  } else {
    const int i = (blk - 64) * 256 + t;  // 0..131071
    const int e = i & 0xffff;
    const float f = (i >> 16) ? w3[e] : w2[e];
    u16 h = f2b(f);
    if (i >> 16) { W3h[e] = h; W3l[e] = f2b(f - b2f(h)); }
    else         { W2h[e] = h; W2l[e] = f2b(f - b2f(h)); }
  }
}

// ---------------- Gram from raw x: full 256x256 per (batch, split) ---------
// 512 threads / 8 waves; wave (wm in {0,128}, wn in {0,64,128,192}) does 128x64.
// Stages x f32 -> hi/lo bf16 LDS; A and B fragments share the staged slab.
// A fragments hoisted once per k-iter: 16+8 = 24 b128 LDS reads/wave/iter.
__global__ __launch_bounds__(512, 2) void gram_kernel(
    const float* __restrict__ x, float* __restrict__ Gp, float* __restrict__ xsum) {
  constexpr int LR = 40;  // +8 pad: 2-way bank aliasing only (free per m136)
  __shared__ u16 lH[256 * LR], lL[256 * LR];
  const int b = blockIdx.x >> 4, s = blockIdx.x & 15;
  const float* Xb = x + (long)b * 1048576 + s * 256;
  const int t = threadIdx.x;
  const int lane = t & 63, wave = t >> 6;
  const int quad = lane >> 4, l16 = lane & 15;
  const int wm = (wave & 1) * 128, wn = (wave >> 1) * 64;
  floatx4 acc[8][4] = {};
  float xacc[2] = {0.f, 0.f};
  for (int kb = 0; kb < 256; kb += 32) {
    __syncthreads();
#pragma unroll
    for (int h = 0; h < 2; ++h) {
      const int item = t + h * 512;
      const int r = item >> 2, qc = (item & 3) * 8;
      const float4 f0 = *(const float4*)(Xb + (long)r * 4096 + kb + qc);
      const float4 f1 = *(const float4*)(Xb + (long)r * 4096 + kb + qc + 4);
      const float f[8] = {f0.x, f0.y, f0.z, f0.w, f1.x, f1.y, f1.z, f1.w};
      union { u16 h8[8]; uint4 q; } uh, ul;
#pragma unroll
      for (int i = 0; i < 8; ++i) {
        const u16 hi = f2b(f[i]);
        uh.h8[i] = hi;
        ul.h8[i] = f2b(f[i] - b2f(hi));
        xacc[h] += f[i];
      }
      *(uint4*)(lH + r * LR + qc) = uh.q;
      *(uint4*)(lL + r * LR + qc) = ul.q;
    }
    __syncthreads();
    short8 ah[8], al[8];
#pragma unroll
    for (int i = 0; i < 8; ++i) {
      ah[i] = *(const short8*)(lH + (wm + i * 16 + l16) * LR + quad * 8);
      al[i] = *(const short8*)(lL + (wm + i * 16 + l16) * LR + quad * 8);
    }
#pragma unroll
    for (int j = 0; j < 4; ++j) {
      const short8 bh = *(const short8*)(lH + (wn + j * 16 + l16) * LR + quad * 8);
      const short8 bl = *(const short8*)(lL + (wn + j * 16 + l16) * LR + quad * 8);
#pragma unroll
      for (int i = 0; i < 8; ++i) {
        acc[i][j] = __builtin_amdgcn_mfma_f32_16x16x32_bf16(ah[i], bh, acc[i][j], 0, 0, 0);
        acc[i][j] = __builtin_amdgcn_mfma_f32_16x16x32_bf16(ah[i], bl, acc[i][j], 0, 0, 0);
        acc[i][j] = __builtin_amdgcn_mfma_f32_16x16x32_bf16(al[i], bh, acc[i][j], 0, 0, 0);
      }
    }
  }
  // xsum: lanes t..t+3 (quad group) share row (item>>2)
#pragma unroll
  for (int h = 0; h < 2; ++h) {
    float v = xacc[h];
    v += __shfl_xor(v, 1);
    v += __shfl_xor(v, 2);
    if ((t & 3) == 0) atomicAdd(&xsum[b * 256 + ((t + h * 512) >> 2)], v);
  }
  float* G = Gp + ((long)b * 16 + s) * 65536;
#pragma unroll
  for (int i = 0; i < 8; ++i) {
    const int row0 = wm + i * 16 + quad * 4;
#pragma unroll
    for (int j = 0; j < 4; ++j) {
      const int col = wn + j * 16 + l16;
#pragma unroll
      for (int r = 0; r < 4; ++r)
        G[(long)(row0 + r) * 256 + col] = acc[i][j][r];
    }
  }
}

// ---------------- Gram split-K reduction + hi/lo split ----------------
__global__ void reduce_g_kernel(const float* __restrict__ Gp, u16* __restrict__ Gh,
                                u16* __restrict__ Gl) {
  const long e = (long)blockIdx.x * 256 + threadIdx.x;  // over 16*65536
  const long base = ((e >> 16) << 20) + (e & 65535);    // b*16*65536 + idx
  float s = 0.f;
#pragma unroll
  for (int i = 0; i < 16; ++i) s += Gp[base + (long)i * 65536];
  u16 h = f2b(s);
  Gh[e] = h;
  Gl[e] = f2b(s - b2f(h));
}

// ---------------- TN GEMM core: 128x128 tile, BK=32, 4 waves ----------------
// EPI: 0 = f32 store, 1 = bf16 hi/lo store, 2 = bf16 hi store
template <bool X3, int EPI>
__global__ __launch_bounds__(256) void gemm_tn(
    const u16* __restrict__ Ah, const u16* __restrict__ Al,
    const u16* __restrict__ Bh, const u16* __restrict__ Bl,
    long aBatch, long bBatch, long oBatch,
    int M, int N, int K, int tilesM,
    float* __restrict__ outF, u16* __restrict__ outH, u16* __restrict__ outL) {
  constexpr int LR = 40;
  __shared__ u16 smem[(X3 ? 4 : 2) * 128 * LR];
  u16* lAh = smem;
  u16* lBh = smem + 128 * LR;
  u16* lAl = X3 ? (smem + 2 * 128 * LR) : nullptr;
  u16* lBl = X3 ? (smem + 3 * 128 * LR) : nullptr;

  const int b = blockIdx.z;
  const int tm = blockIdx.x % tilesM, tn = blockIdx.x / tilesM;
  const u16* Ahb = Ah + (long)b * aBatch;
  const u16* Bhb = Bh + (long)b * bBatch;
  const u16* Alb = X3 ? (Al + (long)b * aBatch) : nullptr;
  const u16* Blb = X3 ? (Bl + (long)b * bBatch) : nullptr;

  const int t = threadIdx.x;
  const int lane = t & 63, wave = t >> 6;
  const int quad = lane >> 4, l16 = lane & 15;
  const int wm = (wave & 1) * 64, wn = (wave >> 1) * 64;
  const int srow = t >> 2, scol = (t & 3) * 8;

  floatx4 acc[4][4] = {};

  for (int kk = 0; kk < K; kk += 32) {
    __syncthreads();
#pragma unroll
    for (int h = 0; h < 2; ++h) {
      const int r = srow + h * 64;
      *(uint4*)(lAh + r * LR + scol) = *(const uint4*)(Ahb + (long)(tm * 128 + r) * K + kk + scol);
      *(uint4*)(lBh + r * LR + scol) = *(const uint4*)(Bhb + (long)(tn * 128 + r) * K + kk + scol);
      if (X3) {
        *(uint4*)(lAl + r * LR + scol) = *(const uint4*)(Alb + (long)(tm * 128 + r) * K + kk + scol);
        *(uint4*)(lBl + r * LR + scol) = *(const uint4*)(Blb + (long)(tn * 128 + r) * K + kk + scol);
      }
    }
    __syncthreads();
    short8 afh[4], bfh[4], afl[4], bfl[4];
#pragma unroll
    for (int i = 0; i < 4; ++i) {
      afh[i] = *(const short8*)(lAh + (wm + i * 16 + l16) * LR + quad * 8);
      bfh[i] = *(const short8*)(lBh + (wn + i * 16 + l16) * LR + quad * 8);
      if (X3) {
        afl[i] = *(const short8*)(lAl + (wm + i * 16 + l16) * LR + quad * 8);
        bfl[i] = *(const short8*)(lBl + (wn + i * 16 + l16) * LR + quad * 8);
      }
    }
#pragma unroll
    for (int i = 0; i < 4; ++i)
#pragma unroll
      for (int j = 0; j < 4; ++j) {
        acc[i][j] = __builtin_amdgcn_mfma_f32_16x16x32_bf16(afh[i], bfh[j], acc[i][j], 0, 0, 0);
        if (X3) {
          acc[i][j] = __builtin_amdgcn_mfma_f32_16x16x32_bf16(afh[i], bfl[j], acc[i][j], 0, 0, 0);
          acc[i][j] = __builtin_amdgcn_mfma_f32_16x16x32_bf16(afl[i], bfh[j], acc[i][j], 0, 0, 0);
        }
      }
  }

  const long obase = (long)b * oBatch;
#pragma unroll
  for (int i = 0; i < 4; ++i) {
    const int mb = tm * 128 + wm + i * 16 + quad * 4;
#pragma unroll
    for (int j = 0; j < 4; ++j) {
      const int n = tn * 128 + wn + j * 16 + l16;
#pragma unroll
      for (int r = 0; r < 4; ++r) {
        const float v = acc[i][j][r];
        const long idx = obase + (long)(mb + r) * N + n;
        if (EPI == 0) {
          outF[idx] = v;
        } else if (EPI == 1) {
          u16 h = f2b(v);
          outH[idx] = h;
          outL[idx] = f2b(v - b2f(h));
        } else {
          outH[idx] = f2b(v);
        }
      }
    }
  }
}

// ---------------- out = Mh * X^T + bb : B operand straight from x f32 -------
// 128x128 tile, BK=32. B staged with in-LDS transpose: e-row PAIRS packed as
// b32 LDS writes (8 per thread per k-iter), XOR-swizzled e-blocks.
__global__ __launch_bounds__(256) void gemm_out(
    const u16* __restrict__ Mh, const float* __restrict__ x,
    const float* __restrict__ bb, float* __restrict__ out) {
  constexpr int LR = 40;
  __shared__ u16 lA[128 * LR], lB[128 * LR];
  const int b = blockIdx.z;
  const int tm = blockIdx.x & 1, tn = blockIdx.x >> 1;  // tilesM=2, tilesN=32
  const u16* Ab = Mh + (long)b * 65536;
  const float* Xb = x + (long)b * 1048576 + tn * 128;
  const int t = threadIdx.x;
  const int lane = t & 63, wave = t >> 6;
  const int quad = lane >> 4, l16 = lane & 15;
  const int wm = (wave & 1) * 64, wn = (wave >> 1) * 64;
  const int erp = (t >> 4) * 2;   // e-row pair base 0..30
  const int n0 = (t & 15) * 8;    // n offset
  floatx4 acc[4][4] = {};
  for (int kk = 0; kk < 256; kk += 32) {
    __syncthreads();
#pragma unroll
    for (int h = 0; h < 2; ++h) {
      const int r = (t >> 2) + h * 64;
      *(uint4*)(lA + r * LR + (t & 3) * 8) =
          *(const uint4*)(Ab + (long)(tm * 128 + r) * 256 + kk + (t & 3) * 8);
    }
    {
      const float4 a0 = *(const float4*)(Xb + (long)(kk + erp) * 4096 + n0);
      const float4 a1 = *(const float4*)(Xb + (long)(kk + erp) * 4096 + n0 + 4);
      const float4 c0 = *(const float4*)(Xb + (long)(kk + erp + 1) * 4096 + n0);
      const float4 c1 = *(const float4*)(Xb + (long)(kk + erp + 1) * 4096 + n0 + 4);
      const float fa[8] = {a0.x, a0.y, a0.z, a0.w, a1.x, a1.y, a1.z, a1.w};
      const float fc[8] = {c0.x, c0.y, c0.z, c0.w, c1.x, c1.y, c1.z, c1.w};
#pragma unroll
      for (int i = 0; i < 8; ++i) {
        const int nl = n0 + i;
        const int sb = (erp >> 3) ^ ((nl >> 4) & 3);  // swizzle e-block
        const unsigned int pk =
            (unsigned int)f2b(fa[i]) | ((unsigned int)f2b(fc[i]) << 16);
        *(unsigned int*)(lB + nl * LR + sb * 8 + (erp & 7)) = pk;
      }
    }
    __syncthreads();
    short8 af[4], bf[4];
#pragma unroll
    for (int i = 0; i < 4; ++i) {
      af[i] = *(const short8*)(lA + (wm + i * 16 + l16) * LR + quad * 8);
      const int n = wn + i * 16 + l16;
      const int rb = quad ^ ((n >> 4) & 3);
      bf[i] = *(const short8*)(lB + n * LR + rb * 8);
    }
#pragma unroll
    for (int i = 0; i < 4; ++i)
#pragma unroll
      for (int j = 0; j < 4; ++j)
        acc[i][j] = __builtin_amdgcn_mfma_f32_16x16x32_bf16(af[i], bf[j], acc[i][j], 0, 0, 0);
  }
  const long obase = (long)b * 1048576;
#pragma unroll
  for (int i = 0; i < 4; ++i) {
    const int mb = tm * 128 + wm + i * 16 + quad * 4;
#pragma unroll
    for (int j = 0; j < 4; ++j) {
      const int n = tn * 128 + wn + j * 16 + l16;
#pragma unroll
      for (int r = 0; r < 4; ++r)
        out[obase + (long)(mb + r) * 4096 + n] = acc[i][j][r] + bb[b * 256 + mb + r];
    }
  }
}

// ---------------- bias prep: s2[b][a]=w2[a,:]·xsum[b], s3 likewise --------
__global__ __launch_bounds__(512) void bias_prep_kernel(
    const float* __restrict__ w2, const float* __restrict__ w3,
    const float* __restrict__ xsum, float* __restrict__ S2, float* __restrict__ S3) {
  __shared__ float xs[256];
  const int b = blockIdx.x, t = threadIdx.x;
  if (t < 256) xs[t] = xsum[b * 256 + t];
  __syncthreads();
  const float* wm = (t < 256) ? w2 : w3;
  const int a = t & 255;
  float s = 0.f;
#pragma unroll 4
  for (int c = 0; c < 256; ++c) s += wm[a * 256 + c] * xs[c];
  if (t < 256) S2[b * 256 + a] = s;
  else         S3[b * 256 + a] = s;
}

// ---------------- softmax pass1: per-block (max, sumexp) ------------------
__global__ __launch_bounds__(256) void softmax_pass1(
    const float* __restrict__ Lt, const float* __restrict__ S2, const float* __restrict__ S3,
    const float* __restrict__ b2, const float* __restrict__ b3,
    float* __restrict__ bm, float* __restrict__ bs) {
  __shared__ float ls2[256], lb2[256];
  __shared__ float redm[4], reds[4];
  const int b = blockIdx.y, blk = blockIdx.x, t = threadIdx.x;
  ls2[t] = S2[b * 256 + t];
  lb2[t] = b2[t];
  __syncthreads();
  const int fw0 = blk * 2048 + t * 8;
  const int d = fw0 >> 8, a0 = fw0 & 255;
  const float c1 = b3[d];
  const float c0 = S3[b * 256 + d] + 4096.f * c1;
  const long base = (long)b * 65536 + fw0;
  float4 v0 = *(const float4*)(Lt + base);
  float4 v1 = *(const float4*)(Lt + base + 4);
  float v[8] = {v0.x, v0.y, v0.z, v0.w, v1.x, v1.y, v1.z, v1.w};
  float m = -3.4e38f;
#pragma unroll
  for (int i = 0; i < 8; ++i) {
    v[i] += lb2[a0 + i] * c0 + c1 * ls2[a0 + i];
    m = fmaxf(m, v[i]);
  }
  for (int o = 32; o; o >>= 1) m = fmaxf(m, __shfl_xor(m, o));
  const int wid = t >> 6, lane = t & 63;
  if (lane == 0) redm[wid] = m;
  __syncthreads();
  const float bmax = fmaxf(fmaxf(redm[0], redm[1]), fmaxf(redm[2], redm[3]));
  float s = 0.f;
#pragma unroll
  for (int i = 0; i < 8; ++i) s += __expf(v[i] - bmax);
  for (int o = 32; o; o >>= 1) s += __shfl_xor(s, o);
  if (lane == 0) reds[wid] = s;
  __syncthreads();
  if (t == 0) {
    bm[b * 32 + blk] = bmax;
    bs[b * 32 + blk] = reds[0] + reds[1] + reds[2] + reds[3];
  }
}

// ------- softmax pass3: inline combine + write WT bf16 (coalesced) ---------
__global__ __launch_bounds__(256) void softmax_pass3(
    const float* __restrict__ Lt, const float* __restrict__ S2, const float* __restrict__ S3,
    const float* __restrict__ b2, const float* __restrict__ b3,
    const float* __restrict__ bm, const float* __restrict__ bs,
    u16* __restrict__ WTh) {
  __shared__ float ls2[256], lb2[256];
  __shared__ float sM, sInv;
  const int b = blockIdx.y, blk = blockIdx.x, t = threadIdx.x;
  if (t < 64) {  // combine 32 block pairs (wave 0 only)
    const float m = (t < 32) ? bm[b * 32 + t] : -3.4e38f;
    float s = (t < 32) ? bs[b * 32 + t] : 0.f;
    float M = m;
    for (int o = 32; o; o >>= 1) M = fmaxf(M, __shfl_xor(M, o));
    s *= __expf(m - M);
    for (int o = 32; o; o >>= 1) s += __shfl_xor(s, o);
    if (t == 0) { sM = M; sInv = 1.0f / s; }
  }
  ls2[t] = S2[b * 256 + t];
  lb2[t] = b2[t];
  __syncthreads();
  const float M = sM, inv = sInv;
  const int fw0 = blk * 2048 + t * 8;
  const int d = fw0 >> 8, a0 = fw0 & 255;
  const float c1 = b3[d];
  const float c0 = S3[b * 256 + d] + 4096.f * c1;
  const long base = (long)b * 65536 + fw0;
  float4 v0 = *(const float4*)(Lt + base);
  float4 v1 = *(const float4*)(Lt + base + 4);
  float v[8] = {v0.x, v0.y, v0.z, v0.w, v1.x, v1.y, v1.z, v1.w};
  union { u16 h[8]; uint4 q; } o;
#pragma unroll
  for (int i = 0; i < 8; ++i) {
    const float vv = v[i] + lb2[a0 + i] * c0 + c1 * ls2[a0 + i];
    o.h[i] = f2b(__expf(vv - M) * inv);
  }
  *(uint4*)(WTh + base) = o.q;
}

// ---------------- bb[b][d] = sum_c weight[c][d]*b1[c] ----------------
__global__ void bb_kernel(const u16* __restrict__ WTh, const float* __restrict__ b1,
                          float* __restrict__ bb) {
  const int b = blockIdx.x, d = threadIdx.x;
  const u16* row = WTh + (long)b * 65536 + d * 256;
  float s = 0.f;
#pragma unroll 4
  for (int c = 0; c < 256; ++c) s += b2f(row[c]) * b1[c];
  bb[b * 256 + d] = s;
}

extern "C" void kernel_launch(void* const* d_in, const int* in_sizes, int n_in,
                              void* d_out, int out_size, void* d_ws, size_t ws_size,
                              hipStream_t stream) {
  const float* x  = (const float*)d_in[0];
  const float* w1 = (const float*)d_in[1];
  const float* b1 = (const float*)d_in[2];
  const float* w2 = (const float*)d_in[3];
  const float* b2 = (const float*)d_in[4];
  const float* w3 = (const float*)d_in[5];
  const float* b3 = (const float*)d_in[6];
  float* out = (float*)d_out;

  char* ws = (char*)d_ws;
  size_t off = 0;
  auto alloc = [&](size_t bytes) {
    void* p = ws + off;
    off += (bytes + 255) & ~(size_t)255;
    return p;
  };
  float* Gp = (float*)alloc(16ull * 16 * 65536 * 4);   // 64 MiB split-K partials
  u16* Gh   = (u16*)alloc(16ull * 65536 * 2);
  u16* Gl   = (u16*)alloc(16ull * 65536 * 2);
  u16* T3h  = (u16*)alloc(16ull * 65536 * 2);
  u16* T3l  = (u16*)alloc(16ull * 65536 * 2);
  float* Lb = (float*)alloc(16ull * 65536 * 4);        // Lt[d][a]
  u16* WTh  = (u16*)alloc(16ull * 65536 * 2);
  u16* Mh   = (u16*)alloc(16ull * 65536 * 2);
  u16* W1Th = (u16*)alloc(65536 * 2);
  u16* W2h  = (u16*)alloc(65536 * 2);
  u16* W2l  = (u16*)alloc(65536 * 2);
  u16* W3h  = (u16*)alloc(65536 * 2);
  u16* W3l  = (u16*)alloc(65536 * 2);
  float* xsum = (float*)alloc(16 * 256 * 4);
  float* S2   = (float*)alloc(16 * 256 * 4);
  float* S3   = (float*)alloc(16 * 256 * 4);
  float* bmx  = (float*)alloc(16 * 32 * 4);
  float* bsx  = (float*)alloc(16 * 32 * 4);
  float* bb   = (float*)alloc(16 * 256 * 4);

  hipMemsetAsync(xsum, 0, 16 * 256 * 4, stream);
  prep_w_kernel<<<576, 256, 0, stream>>>(w1, w2, w3, W1Th, W2h, W2l, W3h, W3l);

  // Gram partials straight from x: 16 batches x 16 n-splits, full 256x256 each.
  gram_kernel<<<256, 512, 0, stream>>>(x, Gp, xsum);
  reduce_g_kernel<<<4096, 256, 0, stream>>>(Gp, Gh, Gl);

  // T3 = W3 * G (G symmetric -> TN ok). M=N=K=256.
  gemm_tn<true, 1><<<dim3(4, 1, 16), 256, 0, stream>>>(
      W3h, W3l, Gh, Gl, 0, 65536, 65536,
      256, 256, 256, 2, nullptr, T3h, T3l);
  // Lt = T3 * W2^T  ->  Lt[d][a] = logits[a][d].
  gemm_tn<true, 0><<<dim3(4, 1, 16), 256, 0, stream>>>(
      T3h, T3l, W2h, W2l, 65536, 0, 65536,
      256, 256, 256, 2, Lb, nullptr, nullptr);

  // softmax: bias prep + pass1 + fused combine/write pass3
  bias_prep_kernel<<<16, 512, 0, stream>>>(w2, w3, xsum, S2, S3);
  softmax_pass1<<<dim3(32, 16), 256, 0, stream>>>(Lb, S2, S3, b2, b3, bmx, bsx);
  softmax_pass3<<<dim3(32, 16), 256, 0, stream>>>(Lb, S2, S3, b2, b3, bmx, bsx, WTh);

  // out-chain: Mh = WT*W1T (bf16), bb = WT·b1, out = Mh*X^T + bb
  bb_kernel<<<16, 256, 0, stream>>>(WTh, b1, bb);
  gemm_tn<false, 2><<<dim3(4, 1, 16), 256, 0, stream>>>(
      WTh, nullptr, W1Th, nullptr, 65536, 0, 65536,
      256, 256, 256, 2, nullptr, Mh, nullptr);
  gemm_out<<<dim3(64, 1, 16), 256, 0, stream>>>(Mh, x, bb, out);
}

// Round 6
// 238.981 us; speedup vs baseline: 1.0626x; 1.0626x over previous
//
#include <hip/hip_runtime.h>

// GlobalChannelAttention: B=16, C=256, H*W=4096
//
// Pipeline (TN-form GEMMs: C[M,N] = sum_k A[m][k]*B[n][k], K contiguous):
//   1. prep_w: w1 -> W1Th (bf16 transposed), w2/w3 -> hi/lo bf16
//   2. gram: G[b] = X X^T read DIRECTLY from x f32 (hi/lo split in staging),
//      one 512-thr block per (batch, n-split/16) computes full 256x256;
//      DOUBLE-BUFFERED LDS: prefetch tile k+1 issues before MFMA of tile k,
//      one barrier per k-iter. xsum folded into staging.
//   3. T3 = W3*G (G symmetric), Lt = T3*W2^T == logits TRANSPOSED (Lt[d][a])
//      -- 64x64-tile small GEMMs, 256-block grids (full CU coverage)
//   4. global softmax (pass1 + fused combine/write pass3, coalesced) -> WT bf16
//   5. out = (WT*W1)*X + WT*b1:  Mh = WT*W1T (bf16), bb = WT·b1,
//      out = Mh*X^T + bb -- B operand read straight from x f32 with in-LDS
//      transpose (pair-packed b32 writes, XOR-swizzled e-blocks).
//
// Precision: logit chain bf16 hi/lo x3 (err ~2^-17 rel); out chain plain bf16.

typedef unsigned short u16;
typedef __attribute__((ext_vector_type(8))) short short8;
typedef __attribute__((ext_vector_type(4))) float floatx4;

__device__ __forceinline__ u16 f2b(float f) {
  union { float f; unsigned int u; } v; v.f = f;
  unsigned int u = v.u;
  return (u16)((u + 0x7fffu + ((u >> 16) & 1u)) >> 16);  // RNE
}
__device__ __forceinline__ float b2f(u16 h) {
  union { unsigned int u; float f; } v; v.u = ((unsigned int)h) << 16;
  return v.f;
}

// ---------------- merged W prep: transpose w1 + split w2/w3 ----------------
__global__ __launch_bounds__(256) void prep_w_kernel(
    const float* __restrict__ w1, const float* __restrict__ w2, const float* __restrict__ w3,
    u16* __restrict__ W1Th, u16* __restrict__ W2h, u16* __restrict__ W2l,
    u16* __restrict__ W3h, u16* __restrict__ W3l) {
  const int blk = blockIdx.x, t = threadIdx.x;
  if (blk < 64) {  // W1Th[e][c] = w1[c][e]
    __shared__ float tile[32][33];
    const int e0 = (blk & 7) * 32, c0 = (blk >> 3) * 32;
    const int tx = t & 31, ty = t >> 5;
#pragma unroll
    for (int i = 0; i < 4; ++i)
      tile[ty + i * 8][tx] = w1[(c0 + ty + i * 8) * 256 + e0 + tx];
    __syncthreads();
#pragma unroll
    for (int i = 0; i < 4; ++i)
      W1Th[(e0 + ty + i * 8) * 256 + c0 + tx] = f2b(tile[tx][ty + i * 8]);
  } else {
    const int i = (blk - 64) * 256 + t;  // 0..131071
    const int e = i & 0xffff;
    const float f = (i >> 16) ? w3[e] : w2[e];
    u16 h = f2b(f);
    if (i >> 16) { W3h[e] = h; W3l[e] = f2b(f - b2f(h)); }
    else         { W2h[e] = h; W2l[e] = f2b(f - b2f(h)); }
  }
}

// ---- stage 8 f32 -> hi/lo bf16 LDS (one uint4 each) + running sum --------
__device__ __forceinline__ void stage8(const float4 a, const float4 b,
                                       u16* dH, u16* dL, float& xa) {
  const float f[8] = {a.x, a.y, a.z, a.w, b.x, b.y, b.z, b.w};
  union { u16 h8[8]; uint4 q; } uh, ul;
#pragma unroll
  for (int i = 0; i < 8; ++i) {
    const u16 hi = f2b(f[i]);
    uh.h8[i] = hi;
    ul.h8[i] = f2b(f[i] - b2f(hi));
    xa += f[i];
  }
  *(uint4*)dH = uh.q;
  *(uint4*)dL = ul.q;
}

// ---------------- Gram from raw x: full 256x256 per (batch, split) ---------
// 512 threads / 8 waves; wave (wm in {0,128}, wn in {0,64,128,192}) does 128x64.
// Double-buffered LDS; prefetch k+1 issued before MFMA of k; 1 barrier/iter.
__global__ __launch_bounds__(512, 2) void gram_kernel(
    const float* __restrict__ x, float* __restrict__ Gp, float* __restrict__ xsum) {
  constexpr int LR = 40;  // +8 pad: 2-way bank aliasing only (free per m136)
  __shared__ u16 lH[2][256 * LR], lL[2][256 * LR];  // 80 KB total
  const int b = blockIdx.x >> 4, s = blockIdx.x & 15;
  const float* Xb = x + (long)b * 1048576 + s * 256;
  const int t = threadIdx.x;
  const int lane = t & 63, wave = t >> 6;
  const int quad = lane >> 4, l16 = lane & 15;
  const int wm = (wave & 1) * 128, wn = (wave >> 1) * 64;
  const int r0 = t >> 2, qc = (t & 3) * 8;  // rows 0..127 (h=0), +128 (h=1)
  const int r1 = r0 + 128;
  floatx4 acc[8][4] = {};
  float xa0 = 0.f, xa1 = 0.f;
  float4 p[4];
  p[0] = *(const float4*)(Xb + (long)r0 * 4096 + qc);
  p[1] = *(const float4*)(Xb + (long)r0 * 4096 + qc + 4);
  p[2] = *(const float4*)(Xb + (long)r1 * 4096 + qc);
  p[3] = *(const float4*)(Xb + (long)r1 * 4096 + qc + 4);
  stage8(p[0], p[1], lH[0] + r0 * LR + qc, lL[0] + r0 * LR + qc, xa0);
  stage8(p[2], p[3], lH[0] + r1 * LR + qc, lL[0] + r1 * LR + qc, xa1);
  __syncthreads();
  for (int kb = 0; kb < 8; ++kb) {
    const int cur = kb & 1, nxt = cur ^ 1;
    if (kb < 7) {  // issue next tile's loads; waitcnt lands after MFMA block
      const long kk = (kb + 1) * 32;
      p[0] = *(const float4*)(Xb + (long)r0 * 4096 + kk + qc);
      p[1] = *(const float4*)(Xb + (long)r0 * 4096 + kk + qc + 4);
      p[2] = *(const float4*)(Xb + (long)r1 * 4096 + kk + qc);
      p[3] = *(const float4*)(Xb + (long)r1 * 4096 + kk + qc + 4);
    }
    const u16* cH = lH[cur];
    const u16* cL = lL[cur];
#pragma unroll
    for (int j = 0; j < 4; ++j) {
      const short8 bh = *(const short8*)(cH + (wn + j * 16 + l16) * LR + quad * 8);
      const short8 bl = *(const short8*)(cL + (wn + j * 16 + l16) * LR + quad * 8);
#pragma unroll
      for (int i = 0; i < 8; ++i) {
        const short8 ah = *(const short8*)(cH + (wm + i * 16 + l16) * LR + quad * 8);
        const short8 al = *(const short8*)(cL + (wm + i * 16 + l16) * LR + quad * 8);
        acc[i][j] = __builtin_amdgcn_mfma_f32_16x16x32_bf16(ah, bh, acc[i][j], 0, 0, 0);
        acc[i][j] = __builtin_amdgcn_mfma_f32_16x16x32_bf16(ah, bl, acc[i][j], 0, 0, 0);
        acc[i][j] = __builtin_amdgcn_mfma_f32_16x16x32_bf16(al, bh, acc[i][j], 0, 0, 0);
      }
    }
    if (kb < 7) {
      stage8(p[0], p[1], lH[nxt] + r0 * LR + qc, lL[nxt] + r0 * LR + qc, xa0);
      stage8(p[2], p[3], lH[nxt] + r1 * LR + qc, lL[nxt] + r1 * LR + qc, xa1);
    }
    __syncthreads();
  }
  // xsum: lanes in a quad share a row
  {
    float v = xa0;
    v += __shfl_xor(v, 1);
    v += __shfl_xor(v, 2);
    if ((t & 3) == 0) atomicAdd(&xsum[b * 256 + r0], v);
    v = xa1;
    v += __shfl_xor(v, 1);
    v += __shfl_xor(v, 2);
    if ((t & 3) == 0) atomicAdd(&xsum[b * 256 + r1], v);
  }
  float* G = Gp + ((long)b * 16 + s) * 65536;
#pragma unroll
  for (int i = 0; i < 8; ++i) {
    const int row0 = wm + i * 16 + quad * 4;
#pragma unroll
    for (int j = 0; j < 4; ++j) {
      const int col = wn + j * 16 + l16;
#pragma unroll
      for (int r = 0; r < 4; ++r)
        G[(long)(row0 + r) * 256 + col] = acc[i][j][r];
    }
  }
}

// ---------------- Gram split-K reduction + hi/lo split ----------------
__global__ void reduce_g_kernel(const float* __restrict__ Gp, u16* __restrict__ Gh,
                                u16* __restrict__ Gl) {
  const long e = (long)blockIdx.x * 256 + threadIdx.x;  // over 16*65536
  const long base = ((e >> 16) << 20) + (e & 65535);    // b*16*65536 + idx
  float s = 0.f;
#pragma unroll
  for (int i = 0; i < 16; ++i) s += Gp[base + (long)i * 65536];
  u16 h = f2b(s);
  Gh[e] = h;
  Gl[e] = f2b(s - b2f(h));
}

// ------- small 256x256x256 TN GEMM: 64x64 tiles, 256-block grid ------------
// EPI: 0 = f32 store, 1 = bf16 hi/lo store, 2 = bf16 hi store
template <bool X3, int EPI>
__global__ __launch_bounds__(256) void gemm_small(
    const u16* __restrict__ Ah, const u16* __restrict__ Al,
    const u16* __restrict__ Bh, const u16* __restrict__ Bl,
    long aBatch, long bBatch, long oBatch,
    float* __restrict__ outF, u16* __restrict__ outH, u16* __restrict__ outL) {
  constexpr int LR = 40;
  __shared__ u16 smem[(X3 ? 4 : 2) * 64 * LR];
  u16* lAh = smem;
  u16* lBh = smem + 64 * LR;
  u16* lAl = X3 ? (smem + 2 * 64 * LR) : nullptr;
  u16* lBl = X3 ? (smem + 3 * 64 * LR) : nullptr;
  const int b = blockIdx.z;
  const int tm = blockIdx.x & 3, tn = blockIdx.x >> 2;  // 4x4 tiles of 64
  const u16* Ahb = Ah + (long)b * aBatch + (long)tm * 64 * 256;
  const u16* Bhb = Bh + (long)b * bBatch + (long)tn * 64 * 256;
  const u16* Alb = X3 ? (Al + (long)b * aBatch + (long)tm * 64 * 256) : nullptr;
  const u16* Blb = X3 ? (Bl + (long)b * bBatch + (long)tn * 64 * 256) : nullptr;
  const int t = threadIdx.x;
  const int lane = t & 63, wave = t >> 6;
  const int quad = lane >> 4, l16 = lane & 15;
  const int wm = (wave & 1) * 32, wn = (wave >> 1) * 32;
  const int r = t >> 2, qc = (t & 3) * 8;  // 64 rows x 4 col-groups
  floatx4 acc[2][2] = {};
  for (int kk = 0; kk < 256; kk += 32) {
    __syncthreads();
    *(uint4*)(lAh + r * LR + qc) = *(const uint4*)(Ahb + (long)r * 256 + kk + qc);
    *(uint4*)(lBh + r * LR + qc) = *(const uint4*)(Bhb + (long)r * 256 + kk + qc);
    if (X3) {
      *(uint4*)(lAl + r * LR + qc) = *(const uint4*)(Alb + (long)r * 256 + kk + qc);
      *(uint4*)(lBl + r * LR + qc) = *(const uint4*)(Blb + (long)r * 256 + kk + qc);
    }
    __syncthreads();
    short8 afh[2], bfh[2], afl[2], bfl[2];
#pragma unroll
    for (int i = 0; i < 2; ++i) {
      afh[i] = *(const short8*)(lAh + (wm + i * 16 + l16) * LR + quad * 8);
      bfh[i] = *(const short8*)(lBh + (wn + i * 16 + l16) * LR + quad * 8);
      if (X3) {
        afl[i] = *(const short8*)(lAl + (wm + i * 16 + l16) * LR + quad * 8);
        bfl[i] = *(const short8*)(lBl + (wn + i * 16 + l16) * LR + quad * 8);
      }
    }
#pragma unroll
    for (int i = 0; i < 2; ++i)
#pragma unroll
      for (int j = 0; j < 2; ++j) {
        acc[i][j] = __builtin_amdgcn_mfma_f32_16x16x32_bf16(afh[i], bfh[j], acc[i][j], 0, 0, 0);
        if (X3) {
          acc[i][j] = __builtin_amdgcn_mfma_f32_16x16x32_bf16(afh[i], bfl[j], acc[i][j], 0, 0, 0);
          acc[i][j] = __builtin_amdgcn_mfma_f32_16x16x32_bf16(afl[i], bfh[j], acc[i][j], 0, 0, 0);
        }
      }
  }
  const long obase = (long)b * oBatch;
#pragma unroll
  for (int i = 0; i < 2; ++i) {
    const int mb = tm * 64 + wm + i * 16 + quad * 4;
#pragma unroll
    for (int j = 0; j < 2; ++j) {
      const int n = tn * 64 + wn + j * 16 + l16;
#pragma unroll
      for (int rr = 0; rr < 4; ++rr) {
        const float v = acc[i][j][rr];
        const long idx = obase + (long)(mb + rr) * 256 + n;
        if (EPI == 0) {
          outF[idx] = v;
        } else if (EPI == 1) {
          u16 h = f2b(v);
          outH[idx] = h;
          outL[idx] = f2b(v - b2f(h));
        } else {
          outH[idx] = f2b(v);
        }
      }
    }
  }
}

// ---------------- out = Mh * X^T + bb : B operand straight from x f32 -------
// 128x128 tile, BK=32. B staged with in-LDS transpose: e-row PAIRS packed as
// b32 LDS writes (8 per thread per k-iter), XOR-swizzled e-blocks.
__global__ __launch_bounds__(256) void gemm_out(
    const u16* __restrict__ Mh, const float* __restrict__ x,
    const float* __restrict__ bb, float* __restrict__ out) {
  constexpr int LR = 40;
  __shared__ u16 lA[128 * LR], lB[128 * LR];
  const int b = blockIdx.z;
  const int tm = blockIdx.x & 1, tn = blockIdx.x >> 1;  // tilesM=2, tilesN=32
  const u16* Ab = Mh + (long)b * 65536;
  const float* Xb = x + (long)b * 1048576 + tn * 128;
  const int t = threadIdx.x;
  const int lane = t & 63, wave = t >> 6;
  const int quad = lane >> 4, l16 = lane & 15;
  const int wm = (wave & 1) * 64, wn = (wave >> 1) * 64;
  const int erp = (t >> 4) * 2;   // e-row pair base 0..30
  const int n0 = (t & 15) * 8;    // n offset
  floatx4 acc[4][4] = {};
  for (int kk = 0; kk < 256; kk += 32) {
    __syncthreads();
#pragma unroll
    for (int h = 0; h < 2; ++h) {
      const int r = (t >> 2) + h * 64;
      *(uint4*)(lA + r * LR + (t & 3) * 8) =
          *(const uint4*)(Ab + (long)(tm * 128 + r) * 256 + kk + (t & 3) * 8);
    }
    {
      const float4 a0 = *(const float4*)(Xb + (long)(kk + erp) * 4096 + n0);
      const float4 a1 = *(const float4*)(Xb + (long)(kk + erp) * 4096 + n0 + 4);
      const float4 c0 = *(const float4*)(Xb + (long)(kk + erp + 1) * 4096 + n0);
      const float4 c1 = *(const float4*)(Xb + (long)(kk + erp + 1) * 4096 + n0 + 4);
      const float fa[8] = {a0.x, a0.y, a0.z, a0.w, a1.x, a1.y, a1.z, a1.w};
      const float fc[8] = {c0.x, c0.y, c0.z, c0.w, c1.x, c1.y, c1.z, c1.w};
#pragma unroll
      for (int i = 0; i < 8; ++i) {
        const int nl = n0 + i;
        const int sb = (erp >> 3) ^ ((nl >> 4) & 3);  // swizzle e-block
        const unsigned int pk =
            (unsigned int)f2b(fa[i]) | ((unsigned int)f2b(fc[i]) << 16);
        *(unsigned int*)(lB + nl * LR + sb * 8 + (erp & 7)) = pk;
      }
    }
    __syncthreads();
    short8 af[4], bf[4];
#pragma unroll
    for (int i = 0; i < 4; ++i) {
      af[i] = *(const short8*)(lA + (wm + i * 16 + l16) * LR + quad * 8);
      const int n = wn + i * 16 + l16;
      const int rb = quad ^ ((n >> 4) & 3);
      bf[i] = *(const short8*)(lB + n * LR + rb * 8);
    }
#pragma unroll
    for (int i = 0; i < 4; ++i)
#pragma unroll
      for (int j = 0; j < 4; ++j)
        acc[i][j] = __builtin_amdgcn_mfma_f32_16x16x32_bf16(af[i], bf[j], acc[i][j], 0, 0, 0);
  }
  const long obase = (long)b * 1048576;
#pragma unroll
  for (int i = 0; i < 4; ++i) {
    const int mb = tm * 128 + wm + i * 16 + quad * 4;
#pragma unroll
    for (int j = 0; j < 4; ++j) {
      const int n = tn * 128 + wn + j * 16 + l16;
#pragma unroll
      for (int r = 0; r < 4; ++r)
        out[obase + (long)(mb + r) * 4096 + n] = acc[i][j][r] + bb[b * 256 + mb + r];
    }
  }
}

// ---------------- bias prep: s2[b][a]=w2[a,:]·xsum[b], s3 likewise --------
__global__ __launch_bounds__(512) void bias_prep_kernel(
    const float* __restrict__ w2, const float* __restrict__ w3,
    const float* __restrict__ xsum, float* __restrict__ S2, float* __restrict__ S3) {
  __shared__ float xs[256];
  const int b = blockIdx.x, t = threadIdx.x;
  if (t < 256) xs[t] = xsum[b * 256 + t];
  __syncthreads();
  const float* wm = (t < 256) ? w2 : w3;
  const int a = t & 255;
  float s = 0.f;
#pragma unroll 4
  for (int c = 0; c < 256; ++c) s += wm[a * 256 + c] * xs[c];
  if (t < 256) S2[b * 256 + a] = s;
  else         S3[b * 256 + a] = s;
}

// ---------------- softmax pass1: per-block (max, sumexp) ------------------
__global__ __launch_bounds__(256) void softmax_pass1(
    const float* __restrict__ Lt, const float* __restrict__ S2, const float* __restrict__ S3,
    const float* __restrict__ b2, const float* __restrict__ b3,
    float* __restrict__ bm, float* __restrict__ bs) {
  __shared__ float ls2[256], lb2[256];
  __shared__ float redm[4], reds[4];
  const int b = blockIdx.y, blk = blockIdx.x, t = threadIdx.x;
  ls2[t] = S2[b * 256 + t];
  lb2[t] = b2[t];
  __syncthreads();
  const int fw0 = blk * 2048 + t * 8;
  const int d = fw0 >> 8, a0 = fw0 & 255;
  const float c1 = b3[d];
  const float c0 = S3[b * 256 + d] + 4096.f * c1;
  const long base = (long)b * 65536 + fw0;
  float4 v0 = *(const float4*)(Lt + base);
  float4 v1 = *(const float4*)(Lt + base + 4);
  float v[8] = {v0.x, v0.y, v0.z, v0.w, v1.x, v1.y, v1.z, v1.w};
  float m = -3.4e38f;
#pragma unroll
  for (int i = 0; i < 8; ++i) {
    v[i] += lb2[a0 + i] * c0 + c1 * ls2[a0 + i];
    m = fmaxf(m, v[i]);
  }
  for (int o = 32; o; o >>= 1) m = fmaxf(m, __shfl_xor(m, o));
  const int wid = t >> 6, lane = t & 63;
  if (lane == 0) redm[wid] = m;
  __syncthreads();
  const float bmax = fmaxf(fmaxf(redm[0], redm[1]), fmaxf(redm[2], redm[3]));
  float s = 0.f;
#pragma unroll
  for (int i = 0; i < 8; ++i) s += __expf(v[i] - bmax);
  for (int o = 32; o; o >>= 1) s += __shfl_xor(s, o);
  if (lane == 0) reds[wid] = s;
  __syncthreads();
  if (t == 0) {
    bm[b * 32 + blk] = bmax;
    bs[b * 32 + blk] = reds[0] + reds[1] + reds[2] + reds[3];
  }
}

// ------- softmax pass3: inline combine + write WT bf16 (coalesced) ---------
__global__ __launch_bounds__(256) void softmax_pass3(
    const float* __restrict__ Lt, const float* __restrict__ S2, const float* __restrict__ S3,
    const float* __restrict__ b2, const float* __restrict__ b3,
    const float* __restrict__ bm, const float* __restrict__ bs,
    u16* __restrict__ WTh) {
  __shared__ float ls2[256], lb2[256];
  __shared__ float sM, sInv;
  const int b = blockIdx.y, blk = blockIdx.x, t = threadIdx.x;
  if (t < 64) {  // combine 32 block pairs (wave 0 only)
    const float m = (t < 32) ? bm[b * 32 + t] : -3.4e38f;
    float s = (t < 32) ? bs[b * 32 + t] : 0.f;
    float M = m;
    for (int o = 32; o; o >>= 1) M = fmaxf(M, __shfl_xor(M, o));
    s *= __expf(m - M);
    for (int o = 32; o; o >>= 1) s += __shfl_xor(s, o);
    if (t == 0) { sM = M; sInv = 1.0f / s; }
  }
  ls2[t] = S2[b * 256 + t];
  lb2[t] = b2[t];
  __syncthreads();
  const float M = sM, inv = sInv;
  const int fw0 = blk * 2048 + t * 8;
  const int d = fw0 >> 8, a0 = fw0 & 255;
  const float c1 = b3[d];
  const float c0 = S3[b * 256 + d] + 4096.f * c1;
  const long base = (long)b * 65536 + fw0;
  float4 v0 = *(const float4*)(Lt + base);
  float4 v1 = *(const float4*)(Lt + base + 4);
  float v[8] = {v0.x, v0.y, v0.z, v0.w, v1.x, v1.y, v1.z, v1.w};
  union { u16 h[8]; uint4 q; } o;
#pragma unroll
  for (int i = 0; i < 8; ++i) {
    const float vv = v[i] + lb2[a0 + i] * c0 + c1 * ls2[a0 + i];
    o.h[i] = f2b(__expf(vv - M) * inv);
  }
  *(uint4*)(WTh + base) = o.q;
}

// ---------------- bb[b][d] = sum_c weight[c][d]*b1[c] ----------------
__global__ void bb_kernel(const u16* __restrict__ WTh, const float* __restrict__ b1,
                          float* __restrict__ bb) {
  const int b = blockIdx.x, d = threadIdx.x;
  const u16* row = WTh + (long)b * 65536 + d * 256;
  float s = 0.f;
#pragma unroll 4
  for (int c = 0; c < 256; ++c) s += b2f(row[c]) * b1[c];
  bb[b * 256 + d] = s;
}

extern "C" void kernel_launch(void* const* d_in, const int* in_sizes, int n_in,
                              void* d_out, int out_size, void* d_ws, size_t ws_size,
                              hipStream_t stream) {
  const float* x  = (const float*)d_in[0];
  const float* w1 = (const float*)d_in[1];
  const float* b1 = (const float*)d_in[2];
  const float* w2 = (const float*)d_in[3];
  const float* b2 = (const float*)d_in[4];
  const float* w3 = (const float*)d_in[5];
  const float* b3 = (const float*)d_in[6];
  float* out = (float*)d_out;

  char* ws = (char*)d_ws;
  size_t off = 0;
  auto alloc = [&](size_t bytes) {
    void* p = ws + off;
    off += (bytes + 255) & ~(size_t)255;
    return p;
  };
  float* Gp = (float*)alloc(16ull * 16 * 65536 * 4);   // 64 MiB split-K partials
  u16* Gh   = (u16*)alloc(16ull * 65536 * 2);
  u16* Gl   = (u16*)alloc(16ull * 65536 * 2);
  u16* T3h  = (u16*)alloc(16ull * 65536 * 2);
  u16* T3l  = (u16*)alloc(16ull * 65536 * 2);
  float* Lb = (float*)alloc(16ull * 65536 * 4);        // Lt[d][a]
  u16* WTh  = (u16*)alloc(16ull * 65536 * 2);
  u16* Mh   = (u16*)alloc(16ull * 65536 * 2);
  u16* W1Th = (u16*)alloc(65536 * 2);
  u16* W2h  = (u16*)alloc(65536 * 2);
  u16* W2l  = (u16*)alloc(65536 * 2);
  u16* W3h  = (u16*)alloc(65536 * 2);
  u16* W3l  = (u16*)alloc(65536 * 2);
  float* xsum = (float*)alloc(16 * 256 * 4);
  float* S2   = (float*)alloc(16 * 256 * 4);
  float* S3   = (float*)alloc(16 * 256 * 4);
  float* bmx  = (float*)alloc(16 * 32 * 4);
  float* bsx  = (float*)alloc(16 * 32 * 4);
  float* bb   = (float*)alloc(16 * 256 * 4);

  hipMemsetAsync(xsum, 0, 16 * 256 * 4, stream);
  prep_w_kernel<<<576, 256, 0, stream>>>(w1, w2, w3, W1Th, W2h, W2l, W3h, W3l);

  // Gram partials straight from x: 16 batches x 16 n-splits, full 256x256 each.
  gram_kernel<<<256, 512, 0, stream>>>(x, Gp, xsum);
  reduce_g_kernel<<<4096, 256, 0, stream>>>(Gp, Gh, Gl);

  // T3 = W3 * G (G symmetric -> TN ok). 64x64 tiles, 256 blocks.
  gemm_small<true, 1><<<dim3(16, 1, 16), 256, 0, stream>>>(
      W3h, W3l, Gh, Gl, 0, 65536, 65536, nullptr, T3h, T3l);
  // Lt = T3 * W2^T  ->  Lt[d][a] = logits[a][d].
  gemm_small<true, 0><<<dim3(16, 1, 16), 256, 0, stream>>>(
      T3h, T3l, W2h, W2l, 65536, 0, 65536, Lb, nullptr, nullptr);

  // softmax: bias prep + pass1 + fused combine/write pass3
  bias_prep_kernel<<<16, 512, 0, stream>>>(w2, w3, xsum, S2, S3);
  softmax_pass1<<<dim3(32, 16), 256, 0, stream>>>(Lb, S2, S3, b2, b3, bmx, bsx);
  softmax_pass3<<<dim3(32, 16), 256, 0, stream>>>(Lb, S2, S3, b2, b3, bmx, bsx, WTh);

  // out-chain: Mh = WT*W1T (bf16), bb = WT·b1, out = Mh*X^T + bb
  bb_kernel<<<16, 256, 0, stream>>>(WTh, b1, bb);
  gemm_small<false, 2><<<dim3(16, 1, 16), 256, 0, stream>>>(
      WTh, nullptr, W1Th, nullptr, 65536, 0, 65536, nullptr, Mh, nullptr);
  gemm_out<<<dim3(64, 1, 16), 256, 0, stream>>>(Mh, x, bb, out);
}